// Round 1
// baseline (369.501 us; speedup 1.0000x reference)
//
#include <hip/hip_runtime.h>

// Problem: ImageRGB_75952201662701 — Keras-style augmentation pipeline
// inputs [32,512,512,3] f32; flip_h/v [32] bool->int; angle/zoom/delta/contrast [32] f32
// out [32,512,512,3] f32

constexpr int Hh = 512, Ww = 512, Cc = 3, BATCH = 32;
constexpr int HW = Hh * Ww;                  // 262144 pixels / image
constexpr float CTR = 255.5f;                // (512-1)/2

// TF 'reflect' fill: m = mod(i, 2n); m < n ? m : 2n-1-m.  2n=1024 pow2 -> & works for negatives.
__device__ __forceinline__ int reflect1024(int i) {
    int m = i & 1023;
    return (m < 512) ? m : (1023 - m);
}

// Pass 1: flip (index remap) + rotation warp + zoom warp (fused 16-tap gather)
// + brightness clip; writes d_out and accumulates per-(b,c) sums for the mean.
__global__ __launch_bounds__(256) void warp_pass(
    const float* __restrict__ in,
    const int* __restrict__ fh, const int* __restrict__ fv,
    const float* __restrict__ angle, const float* __restrict__ zoom,
    const float* __restrict__ delta,
    float* __restrict__ out, double* __restrict__ sums)
{
    const int b = blockIdx.y;
    const float ang = angle[b];
    const float cs = cosf(ang), sn = sinf(ang);
    const float z  = zoom[b];
    const float dl = delta[b];
    const int fhm = fh[b] ? 511 : 0;   // x in [0,511]: 511 - x == x ^ 511
    const int fvm = fv[b] ? 511 : 0;
    const float* __restrict__ img  = in  + (size_t)b * HW * Cc;
    float* __restrict__       outb = out + (size_t)b * HW * Cc;

    float s0 = 0.f, s1 = 0.f, s2 = 0.f;

    // 128 blocks x 256 threads per image, 8 pixels per thread (stride 32768)
    #pragma unroll 1
    for (int it = 0; it < 8; ++it) {
        const int p = it * 32768 + blockIdx.x * 256 + threadIdx.x;
        const int y = p >> 9, x = p & 511;

        // zoom stage source coords (isotropic)
        const float sx2 = z * ((float)x - CTR) + CTR;
        const float sy2 = z * ((float)y - CTR) + CTR;
        const float x0f = floorf(sx2), y0f = floorf(sy2);
        const float wx = sx2 - x0f, wy = sy2 - y0f;
        const int xx[2] = { reflect1024((int)x0f), reflect1024((int)x0f + 1) };
        const int yy[2] = { reflect1024((int)y0f), reflect1024((int)y0f + 1) };

        float r[2][2][3];
        #pragma unroll
        for (int ky = 0; ky < 2; ++ky) {
            #pragma unroll
            for (int kx = 0; kx < 2; ++kx) {
                // rotation stage: sample rotated image at integer coord (yy[ky], xx[kx])
                const float rx = (float)xx[kx] - CTR;
                const float ry = (float)yy[ky] - CTR;
                const float sx1 = cs * rx - sn * ry + CTR;
                const float sy1 = sn * rx + cs * ry + CTR;
                const float x1f = floorf(sx1), y1f = floorf(sy1);
                const float wx1 = sx1 - x1f, wy1 = sy1 - y1f;
                const int xa = reflect1024((int)x1f)     ^ fhm;
                const int xb = reflect1024((int)x1f + 1) ^ fhm;
                const int ya = reflect1024((int)y1f)     ^ fvm;
                const int yb = reflect1024((int)y1f + 1) ^ fvm;
                const float* p00 = img + (ya * Ww + xa) * Cc;
                const float* p01 = img + (ya * Ww + xb) * Cc;
                const float* p10 = img + (yb * Ww + xa) * Cc;
                const float* p11 = img + (yb * Ww + xb) * Cc;
                const float w1y = 1.f - wy1, w1x = 1.f - wx1;
                #pragma unroll
                for (int c = 0; c < 3; ++c) {
                    // match reference op order: ((img*(1-wy))*(1-wx)) + ... left-assoc
                    r[ky][kx][c] = ((p00[c] * w1y) * w1x) + ((p01[c] * w1y) * wx1)
                                 + ((p10[c] * wy1) * w1x) + ((p11[c] * wy1) * wx1);
                }
            }
        }

        const float w1y = 1.f - wy, w1x = 1.f - wx;
        float v[3];
        #pragma unroll
        for (int c = 0; c < 3; ++c) {
            float t = ((r[0][0][c] * w1y) * w1x) + ((r[0][1][c] * w1y) * wx)
                    + ((r[1][0][c] * wy) * w1x) + ((r[1][1][c] * wy) * wx);
            t = fminf(fmaxf(t + dl, 0.f), 255.f);   // brightness + clip
            v[c] = t;
            outb[p * 3 + c] = t;
        }
        s0 += v[0]; s1 += v[1]; s2 += v[2];
    }

    // block reduce: wave64 shuffle -> LDS across 4 waves -> 3 double atomics
    #pragma unroll
    for (int off = 32; off > 0; off >>= 1) {
        s0 += __shfl_down(s0, off);
        s1 += __shfl_down(s1, off);
        s2 += __shfl_down(s2, off);
    }
    __shared__ float red[4][3];
    const int lane = threadIdx.x & 63, wid = threadIdx.x >> 6;
    if (lane == 0) { red[wid][0] = s0; red[wid][1] = s1; red[wid][2] = s2; }
    __syncthreads();
    if (threadIdx.x == 0) {
        double t0 = (double)red[0][0] + red[1][0] + red[2][0] + red[3][0];
        double t1 = (double)red[0][1] + red[1][1] + red[2][1] + red[3][1];
        double t2 = (double)red[0][2] + red[1][2] + red[2][2] + red[3][2];
        atomicAdd(&sums[b * 3 + 0], t0);
        atomicAdd(&sums[b * 3 + 1], t1);
        atomicAdd(&sums[b * 3 + 2], t2);
    }
}

// Pass 2: contrast about per-channel mean + clip, float4 vectorized, in place.
__global__ __launch_bounds__(256) void contrast_pass(
    float* __restrict__ out, const double* __restrict__ sums,
    const float* __restrict__ contrast)
{
    const int b = blockIdx.y;
    const float f = contrast[b];
    const double invN = 1.0 / (double)HW;
    const float m0 = (float)(sums[b * 3 + 0] * invN);
    const float m1 = (float)(sums[b * 3 + 1] * invN);
    const float m2 = (float)(sums[b * 3 + 2] * invN);

    const int i4 = blockIdx.x * 256 + threadIdx.x;       // float4 index within image
    float4* base = reinterpret_cast<float4*>(out + (size_t)b * HW * Cc);
    float4 v = base[i4];

    int c = (int)(((unsigned)i4 * 4u) % 3u);
    float m;
    m = (c == 0) ? m0 : ((c == 1) ? m1 : m2);
    v.x = fminf(fmaxf((v.x - m) * f + m, 0.f), 255.f); c = (c == 2) ? 0 : c + 1;
    m = (c == 0) ? m0 : ((c == 1) ? m1 : m2);
    v.y = fminf(fmaxf((v.y - m) * f + m, 0.f), 255.f); c = (c == 2) ? 0 : c + 1;
    m = (c == 0) ? m0 : ((c == 1) ? m1 : m2);
    v.z = fminf(fmaxf((v.z - m) * f + m, 0.f), 255.f); c = (c == 2) ? 0 : c + 1;
    m = (c == 0) ? m0 : ((c == 1) ? m1 : m2);
    v.w = fminf(fmaxf((v.w - m) * f + m, 0.f), 255.f);

    base[i4] = v;
}

extern "C" void kernel_launch(void* const* d_in, const int* in_sizes, int n_in,
                              void* d_out, int out_size, void* d_ws, size_t ws_size,
                              hipStream_t stream) {
    const float* in       = (const float*)d_in[0];
    const int*   fh       = (const int*)d_in[1];
    const int*   fv       = (const int*)d_in[2];
    const float* angle    = (const float*)d_in[3];
    const float* zoom     = (const float*)d_in[4];
    const float* delta    = (const float*)d_in[5];
    const float* contrast = (const float*)d_in[6];
    float*  out  = (float*)d_out;
    double* sums = (double*)d_ws;

    // ws is re-poisoned to 0xAA before every timed call — zero the accumulators.
    hipMemsetAsync(d_ws, 0, BATCH * 3 * sizeof(double), stream);

    dim3 blk(256);
    dim3 g1(128, BATCH);                     // 8 pixels/thread
    warp_pass<<<g1, blk, 0, stream>>>(in, fh, fv, angle, zoom, delta, out, sums);

    dim3 g2((HW * Cc / 4) / 256, BATCH);     // 768 blocks/image, float4
    contrast_pass<<<g2, blk, 0, stream>>>(out, sums, contrast);
}

// Round 2
// 337.868 us; speedup vs baseline: 1.0936x; 1.0936x over previous
//
#include <hip/hip_runtime.h>

// ImageRGB_75952201662701 — flip → rotate(bilinear,reflect) → zoom(bilinear,reflect)
// → brightness+clip → contrast(channel-mean)+clip.  [32,512,512,3] f32.
//
// R2: materialize the rotated image in d_ws (as the reference does) to cut the
// scattered gather from 16 taps/pixel (latency-bound, 33% VALU / 14% HBM) to
// 4 taps in a rotate pass + 4 axis-aligned taps in a zoom pass.

constexpr int Hh = 512, Ww = 512, Cc = 3, BATCH = 32;
constexpr int HW = Hh * Ww;
constexpr float CTR = 255.5f;                 // (512-1)/2
constexpr size_t IMG_FLOATS = (size_t)HW * Cc;            // 786432
constexpr size_t ROT_OFF_BYTES = 4096;                    // sums live at ws[0..768)
constexpr size_t ROT_BYTES = (size_t)BATCH * IMG_FLOATS * sizeof(float); // 96 MB

__device__ __forceinline__ int reflect1024(int i) {
    int m = i & 1023;                         // exact for negatives: 2n = 1024 pow2
    return (m < 512) ? m : (1023 - m);
}

// ---------- Pass 1: flip + rotation, materialize rotated image (4-tap gather) ----------
__global__ __launch_bounds__(256) void rotate_pass(
    const float* __restrict__ in,
    const int* __restrict__ fh, const int* __restrict__ fv,
    const float* __restrict__ angle, float* __restrict__ rot)
{
    const int b = blockIdx.y;
    const float ang = angle[b];
    const float cs = cosf(ang), sn = sinf(ang);
    const int fhm = fh[b] ? 511 : 0;          // 511 - x == x ^ 511 for x in [0,511]
    const int fvm = fv[b] ? 511 : 0;
    const float* __restrict__ img = in  + (size_t)b * IMG_FLOATS;
    float* __restrict__       rb  = rot + (size_t)b * IMG_FLOATS;

    // 2 independent pixels per thread (stride 128 rows) for memory-level parallelism
    #pragma unroll
    for (int it = 0; it < 2; ++it) {
        const int p = it * 131072 + blockIdx.x * 256 + threadIdx.x;
        const int y = p >> 9, x = p & 511;
        const float rx = (float)x - CTR, ry = (float)y - CTR;
        const float sx = cs * rx - sn * ry + CTR;
        const float sy = sn * rx + cs * ry + CTR;
        const float xf = floorf(sx), yf = floorf(sy);
        const float wx = sx - xf,  wy = sy - yf;
        const int xa = reflect1024((int)xf)     ^ fhm;
        const int xb = reflect1024((int)xf + 1) ^ fhm;
        const int ya = reflect1024((int)yf)     ^ fvm;
        const int yb = reflect1024((int)yf + 1) ^ fvm;
        const float* p00 = img + (ya * Ww + xa) * Cc;
        const float* p01 = img + (ya * Ww + xb) * Cc;
        const float* p10 = img + (yb * Ww + xa) * Cc;
        const float* p11 = img + (yb * Ww + xb) * Cc;
        const float w1y = 1.f - wy, w1x = 1.f - wx;
        #pragma unroll
        for (int c = 0; c < 3; ++c) {
            // reference op order: ((v*(1-wy))*(1-wx)) + ((v*(1-wy))*wx) + ...
            rb[p * 3 + c] = ((p00[c] * w1y) * w1x) + ((p01[c] * w1y) * wx)
                          + ((p10[c] * wy) * w1x)  + ((p11[c] * wy) * wx);
        }
    }
}

// ---------- Pass 2: zoom (axis-aligned 4-tap) + brightness + clip + channel sums ----------
__global__ __launch_bounds__(256) void zoom_pass(
    const float* __restrict__ rot,
    const float* __restrict__ zoom, const float* __restrict__ delta,
    float* __restrict__ out, double* __restrict__ sums)
{
    const int b = blockIdx.y;
    const float z  = zoom[b];
    const float dl = delta[b];
    const float* __restrict__ rb   = rot + (size_t)b * IMG_FLOATS;
    float* __restrict__       outb = out + (size_t)b * IMG_FLOATS;

    float s0 = 0.f, s1 = 0.f, s2 = 0.f;

    #pragma unroll 1
    for (int it = 0; it < 8; ++it) {
        const int p = it * 32768 + blockIdx.x * 256 + threadIdx.x;
        const int y = p >> 9, x = p & 511;
        const float sx = z * ((float)x - CTR) + CTR;
        const float sy = z * ((float)y - CTR) + CTR;
        const float xf = floorf(sx), yf = floorf(sy);
        const float wx = sx - xf,  wy = sy - yf;
        const int xa = reflect1024((int)xf);
        const int xb = reflect1024((int)xf + 1);
        const int ya = reflect1024((int)yf);
        const int yb = reflect1024((int)yf + 1);
        const float* p00 = rb + (ya * Ww + xa) * Cc;
        const float* p01 = rb + (ya * Ww + xb) * Cc;
        const float* p10 = rb + (yb * Ww + xa) * Cc;
        const float* p11 = rb + (yb * Ww + xb) * Cc;
        const float w1y = 1.f - wy, w1x = 1.f - wx;
        #pragma unroll
        for (int c = 0; c < 3; ++c) {
            float t = ((p00[c] * w1y) * w1x) + ((p01[c] * w1y) * wx)
                    + ((p10[c] * wy) * w1x)  + ((p11[c] * wy) * wx);
            t = fminf(fmaxf(t + dl, 0.f), 255.f);        // brightness + clip
            outb[p * 3 + c] = t;
            if (c == 0) s0 += t; else if (c == 1) s1 += t; else s2 += t;
        }
    }

    #pragma unroll
    for (int off = 32; off > 0; off >>= 1) {
        s0 += __shfl_down(s0, off);
        s1 += __shfl_down(s1, off);
        s2 += __shfl_down(s2, off);
    }
    __shared__ float red[4][3];
    const int lane = threadIdx.x & 63, wid = threadIdx.x >> 6;
    if (lane == 0) { red[wid][0] = s0; red[wid][1] = s1; red[wid][2] = s2; }
    __syncthreads();
    if (threadIdx.x == 0) {
        atomicAdd(&sums[b * 3 + 0], (double)red[0][0] + red[1][0] + red[2][0] + red[3][0]);
        atomicAdd(&sums[b * 3 + 1], (double)red[0][1] + red[1][1] + red[2][1] + red[3][1]);
        atomicAdd(&sums[b * 3 + 2], (double)red[0][2] + red[1][2] + red[2][2] + red[3][2]);
    }
}

// ---------- Pass 3: contrast about per-channel mean + clip (8 x float4 per thread) ----------
__global__ __launch_bounds__(256) void contrast_pass(
    float* __restrict__ out, const double* __restrict__ sums,
    const float* __restrict__ contrast)
{
    const int b = blockIdx.y;
    const float f = contrast[b];
    const double invN = 1.0 / (double)HW;
    const float m0 = (float)(sums[b * 3 + 0] * invN);
    const float m1 = (float)(sums[b * 3 + 1] * invN);
    const float m2 = (float)(sums[b * 3 + 2] * invN);
    float4* base = reinterpret_cast<float4*>(out + (size_t)b * IMG_FLOATS);

    #pragma unroll
    for (int it = 0; it < 8; ++it) {
        const int i4 = it * 24576 + blockIdx.x * 256 + threadIdx.x;
        float4 v = base[i4];
        int c = (int)(((unsigned)i4 * 4u) % 3u);
        float m;
        m = (c == 0) ? m0 : ((c == 1) ? m1 : m2);
        v.x = fminf(fmaxf((v.x - m) * f + m, 0.f), 255.f); c = (c == 2) ? 0 : c + 1;
        m = (c == 0) ? m0 : ((c == 1) ? m1 : m2);
        v.y = fminf(fmaxf((v.y - m) * f + m, 0.f), 255.f); c = (c == 2) ? 0 : c + 1;
        m = (c == 0) ? m0 : ((c == 1) ? m1 : m2);
        v.z = fminf(fmaxf((v.z - m) * f + m, 0.f), 255.f); c = (c == 2) ? 0 : c + 1;
        m = (c == 0) ? m0 : ((c == 1) ? m1 : m2);
        v.w = fminf(fmaxf((v.w - m) * f + m, 0.f), 255.f);
        base[i4] = v;
    }
}

// ---------- Fallback (ws too small): R1's fused 16-tap kernel ----------
__global__ __launch_bounds__(256) void warp_pass_fused(
    const float* __restrict__ in,
    const int* __restrict__ fh, const int* __restrict__ fv,
    const float* __restrict__ angle, const float* __restrict__ zoom,
    const float* __restrict__ delta,
    float* __restrict__ out, double* __restrict__ sums)
{
    const int b = blockIdx.y;
    const float ang = angle[b];
    const float cs = cosf(ang), sn = sinf(ang);
    const float z  = zoom[b];
    const float dl = delta[b];
    const int fhm = fh[b] ? 511 : 0;
    const int fvm = fv[b] ? 511 : 0;
    const float* __restrict__ img  = in  + (size_t)b * IMG_FLOATS;
    float* __restrict__       outb = out + (size_t)b * IMG_FLOATS;

    float s0 = 0.f, s1 = 0.f, s2 = 0.f;

    #pragma unroll 1
    for (int it = 0; it < 8; ++it) {
        const int p = it * 32768 + blockIdx.x * 256 + threadIdx.x;
        const int y = p >> 9, x = p & 511;
        const float sx2 = z * ((float)x - CTR) + CTR;
        const float sy2 = z * ((float)y - CTR) + CTR;
        const float x0f = floorf(sx2), y0f = floorf(sy2);
        const float wx = sx2 - x0f, wy = sy2 - y0f;
        const int xx[2] = { reflect1024((int)x0f), reflect1024((int)x0f + 1) };
        const int yy[2] = { reflect1024((int)y0f), reflect1024((int)y0f + 1) };

        float r[2][2][3];
        #pragma unroll
        for (int ky = 0; ky < 2; ++ky) {
            #pragma unroll
            for (int kx = 0; kx < 2; ++kx) {
                const float rx = (float)xx[kx] - CTR;
                const float ry = (float)yy[ky] - CTR;
                const float sx1 = cs * rx - sn * ry + CTR;
                const float sy1 = sn * rx + cs * ry + CTR;
                const float x1f = floorf(sx1), y1f = floorf(sy1);
                const float wx1 = sx1 - x1f, wy1 = sy1 - y1f;
                const int xa = reflect1024((int)x1f)     ^ fhm;
                const int xb = reflect1024((int)x1f + 1) ^ fhm;
                const int ya = reflect1024((int)y1f)     ^ fvm;
                const int yb = reflect1024((int)y1f + 1) ^ fvm;
                const float* p00 = img + (ya * Ww + xa) * Cc;
                const float* p01 = img + (ya * Ww + xb) * Cc;
                const float* p10 = img + (yb * Ww + xa) * Cc;
                const float* p11 = img + (yb * Ww + xb) * Cc;
                const float w1y = 1.f - wy1, w1x = 1.f - wx1;
                #pragma unroll
                for (int c = 0; c < 3; ++c) {
                    r[ky][kx][c] = ((p00[c] * w1y) * w1x) + ((p01[c] * w1y) * wx1)
                                 + ((p10[c] * wy1) * w1x) + ((p11[c] * wy1) * wx1);
                }
            }
        }
        const float w1y = 1.f - wy, w1x = 1.f - wx;
        #pragma unroll
        for (int c = 0; c < 3; ++c) {
            float t = ((r[0][0][c] * w1y) * w1x) + ((r[0][1][c] * w1y) * wx)
                    + ((r[1][0][c] * wy) * w1x) + ((r[1][1][c] * wy) * wx);
            t = fminf(fmaxf(t + dl, 0.f), 255.f);
            outb[p * 3 + c] = t;
            if (c == 0) s0 += t; else if (c == 1) s1 += t; else s2 += t;
        }
    }
    #pragma unroll
    for (int off = 32; off > 0; off >>= 1) {
        s0 += __shfl_down(s0, off);
        s1 += __shfl_down(s1, off);
        s2 += __shfl_down(s2, off);
    }
    __shared__ float red[4][3];
    const int lane = threadIdx.x & 63, wid = threadIdx.x >> 6;
    if (lane == 0) { red[wid][0] = s0; red[wid][1] = s1; red[wid][2] = s2; }
    __syncthreads();
    if (threadIdx.x == 0) {
        atomicAdd(&sums[b * 3 + 0], (double)red[0][0] + red[1][0] + red[2][0] + red[3][0]);
        atomicAdd(&sums[b * 3 + 1], (double)red[0][1] + red[1][1] + red[2][1] + red[3][1]);
        atomicAdd(&sums[b * 3 + 2], (double)red[0][2] + red[1][2] + red[2][2] + red[3][2]);
    }
}

extern "C" void kernel_launch(void* const* d_in, const int* in_sizes, int n_in,
                              void* d_out, int out_size, void* d_ws, size_t ws_size,
                              hipStream_t stream) {
    const float* in       = (const float*)d_in[0];
    const int*   fh       = (const int*)d_in[1];
    const int*   fv       = (const int*)d_in[2];
    const float* angle    = (const float*)d_in[3];
    const float* zoom     = (const float*)d_in[4];
    const float* delta    = (const float*)d_in[5];
    const float* contrast = (const float*)d_in[6];
    float*  out  = (float*)d_out;
    double* sums = (double*)d_ws;

    // ws re-poisoned to 0xAA each call — zero the sum accumulators.
    hipMemsetAsync(d_ws, 0, BATCH * 3 * sizeof(double), stream);

    dim3 blk(256);
    if (ws_size >= ROT_OFF_BYTES + ROT_BYTES) {
        float* rot = (float*)((char*)d_ws + ROT_OFF_BYTES);
        dim3 g1(512, BATCH);                 // 2 px/thread
        rotate_pass<<<g1, blk, 0, stream>>>(in, fh, fv, angle, rot);
        dim3 g2(128, BATCH);                 // 8 px/thread
        zoom_pass<<<g2, blk, 0, stream>>>(rot, zoom, delta, out, sums);
    } else {
        dim3 g1(128, BATCH);
        warp_pass_fused<<<g1, blk, 0, stream>>>(in, fh, fv, angle, zoom, delta, out, sums);
    }
    dim3 g3(96, BATCH);                      // 8 float4/thread
    contrast_pass<<<g3, blk, 0, stream>>>(out, sums, contrast);
}

// Round 4
// 305.088 us; speedup vs baseline: 1.2111x; 1.1074x over previous
//
#include <hip/hip_runtime.h>

// ImageRGB_75952201662701 — flip → rotate(bilinear,reflect) → zoom(bilinear,reflect)
// → brightness+clip → contrast(channel-mean)+clip.  [32,512,512,3] f32.
//
// R3 (resubmit — broker timeout, never benched): fuse rotate+zoom per output
// tile through LDS. For a 64x16 output tile the zoom taps need rotated-image
// values at a contiguous pre-reflect integer rect (<=97x25 for z<=1.5).
// Compute those rotated pixels once (4-tap gather from a compact 2D input
// footprint -> cache-friendly) into LDS, then zoom-sample from LDS.
// Eliminates the 96MB rot intermediate (192MB HBM round-trip) and fixes the
// rotate gather locality that left R2's rotate_pass latency-bound
// (29% HBM / 19% VALU).

constexpr int Hh = 512, Ww = 512, Cc = 3, BATCH = 32;
constexpr int HW = Hh * Ww;
constexpr float CTR = 255.5f;                 // (512-1)/2
constexpr size_t IMG_FLOATS = (size_t)HW * Cc;

constexpr int TW = 64, TH = 16;               // output tile per block (256 thr)
constexpr int RW = 99, RH = 26;               // LDS rect capacity (Wr<=97, Hr<=25)

__device__ __forceinline__ int reflect1024(int i) {
    int m = i & 1023;                         // exact for negatives: 2n = 1024 pow2
    return (m < 512) ? m : (1023 - m);
}

__global__ __launch_bounds__(256) void warp_fused(
    const float* __restrict__ in,
    const int* __restrict__ fh, const int* __restrict__ fv,
    const float* __restrict__ angle, const float* __restrict__ zoom,
    const float* __restrict__ delta,
    float* __restrict__ out, double* __restrict__ sums)
{
    __shared__ float lds[RH][RW][3];          // 30888 B
    __shared__ float red[4][3];

    const int b = blockIdx.z;
    const float ang = angle[b];
    const float cs = cosf(ang), sn = sinf(ang);
    const float z  = zoom[b];
    const float dl = delta[b];
    const int fhm = fh[b] ? 511 : 0;          // 511 - x == x ^ 511 for x in [0,511]
    const int fvm = fv[b] ? 511 : 0;
    const float* __restrict__ img  = in  + (size_t)b * IMG_FLOATS;
    float* __restrict__       outb = out + (size_t)b * IMG_FLOATS;

    const int X0 = blockIdx.x * TW;
    const int Y0 = blockIdx.y * TH;

    // pre-reflect integer coord range needed by this tile's zoom taps
    // (z > 0 -> sx monotone in x, so corners bound the range)
    const int rx0 = (int)floorf(z * ((float)X0 - CTR) + CTR);
    const int ry0 = (int)floorf(z * ((float)Y0 - CTR) + CTR);
    const int rx1 = (int)floorf(z * ((float)(X0 + TW - 1) - CTR) + CTR) + 1;
    const int ry1 = (int)floorf(z * ((float)(Y0 + TH - 1) - CTR) + CTR) + 1;
    const int Wr = rx1 - rx0 + 1;             // <= 97 for z <= 1.5
    const int Hr = ry1 - ry0 + 1;             // <= 25
    const int N  = Wr * Hr;

    // ---- fill: rotated-image pixels at reflected coords, into LDS rect ----
    {
        unsigned i  = threadIdx.x;
        unsigned ry = i / (unsigned)Wr;       // one division; then incremental
        unsigned rx = i - ry * (unsigned)Wr;
        const unsigned q = 256u / (unsigned)Wr;
        const unsigned r = 256u - q * (unsigned)Wr;
        while (i < (unsigned)N) {
            const int gx = reflect1024(rx0 + (int)rx);
            const int gy = reflect1024(ry0 + (int)ry);
            const float fx = (float)gx - CTR, fy = (float)gy - CTR;
            // reference: sx = a*x + b*y + cx with a=cos, b=-sin  (IEEE-identical)
            const float sx = cs * fx - sn * fy + CTR;
            const float sy = sn * fx + cs * fy + CTR;
            const float xf = floorf(sx), yf = floorf(sy);
            const float wx = sx - xf, wy = sy - yf;
            const int xa = reflect1024((int)xf)     ^ fhm;
            const int xb = reflect1024((int)xf + 1) ^ fhm;
            const int ya = reflect1024((int)yf)     ^ fvm;
            const int yb = reflect1024((int)yf + 1) ^ fvm;
            const float* p00 = img + (ya * Ww + xa) * Cc;
            const float* p01 = img + (ya * Ww + xb) * Cc;
            const float* p10 = img + (yb * Ww + xa) * Cc;
            const float* p11 = img + (yb * Ww + xb) * Cc;
            const float w1y = 1.f - wy, w1x = 1.f - wx;
            #pragma unroll
            for (int c = 0; c < 3; ++c) {
                lds[ry][rx][c] = ((p00[c] * w1y) * w1x) + ((p01[c] * w1y) * wx)
                               + ((p10[c] * wy) * w1x)  + ((p11[c] * wy) * wx);
            }
            i += 256;
            rx += r; ry += q;
            if (rx >= (unsigned)Wr) { rx -= (unsigned)Wr; ry += 1u; }
        }
    }
    __syncthreads();

    // ---- zoom from LDS + brightness + clip + store + channel sums ----
    const int tx  = threadIdx.x & 63;
    const int ty0 = threadIdx.x >> 6;
    const float sx = z * ((float)(X0 + tx) - CTR) + CTR;
    const float xf = floorf(sx);
    const float wx = sx - xf;
    const int lxa = (int)xf - rx0;            // in [0, Wr-2]
    const float w1x = 1.f - wx;

    float s0 = 0.f, s1 = 0.f, s2 = 0.f;
    #pragma unroll
    for (int k = 0; k < 4; ++k) {
        const int y = Y0 + ty0 + (k << 2);    // wave writes one full 64-px row
        const float sy = z * ((float)y - CTR) + CTR;
        const float yf = floorf(sy);
        const float wy = sy - yf;
        const int lya = (int)yf - ry0;        // in [0, Hr-2]
        const float w1y = 1.f - wy;
        float* o = outb + (size_t)((y << 9) + X0 + tx) * 3;
        #pragma unroll
        for (int c = 0; c < 3; ++c) {
            float t = ((lds[lya][lxa][c] * w1y) * w1x) + ((lds[lya][lxa + 1][c] * w1y) * wx)
                    + ((lds[lya + 1][lxa][c] * wy) * w1x) + ((lds[lya + 1][lxa + 1][c] * wy) * wx);
            t = fminf(fmaxf(t + dl, 0.f), 255.f);     // brightness + clip
            o[c] = t;
            if (c == 0) s0 += t; else if (c == 1) s1 += t; else s2 += t;
        }
    }

    // block reduce -> 3 double atomics (256 blocks/image contend lightly)
    #pragma unroll
    for (int off = 32; off > 0; off >>= 1) {
        s0 += __shfl_down(s0, off);
        s1 += __shfl_down(s1, off);
        s2 += __shfl_down(s2, off);
    }
    const int lane = threadIdx.x & 63, wid = threadIdx.x >> 6;
    if (lane == 0) { red[wid][0] = s0; red[wid][1] = s1; red[wid][2] = s2; }
    __syncthreads();
    if (threadIdx.x == 0) {
        atomicAdd(&sums[b * 3 + 0], (double)red[0][0] + red[1][0] + red[2][0] + red[3][0]);
        atomicAdd(&sums[b * 3 + 1], (double)red[0][1] + red[1][1] + red[2][1] + red[3][1]);
        atomicAdd(&sums[b * 3 + 2], (double)red[0][2] + red[1][2] + red[2][2] + red[3][2]);
    }
}

// ---------- Pass 2: contrast about per-channel mean + clip (8 x float4/thread) ----------
__global__ __launch_bounds__(256) void contrast_pass(
    float* __restrict__ out, const double* __restrict__ sums,
    const float* __restrict__ contrast)
{
    const int b = blockIdx.y;
    const float f = contrast[b];
    const double invN = 1.0 / (double)HW;
    const float m0 = (float)(sums[b * 3 + 0] * invN);
    const float m1 = (float)(sums[b * 3 + 1] * invN);
    const float m2 = (float)(sums[b * 3 + 2] * invN);
    float4* base = reinterpret_cast<float4*>(out + (size_t)b * IMG_FLOATS);

    #pragma unroll
    for (int it = 0; it < 8; ++it) {
        const int i4 = it * 24576 + blockIdx.x * 256 + threadIdx.x;
        float4 v = base[i4];
        int c = (int)(((unsigned)i4 * 4u) % 3u);
        float m;
        m = (c == 0) ? m0 : ((c == 1) ? m1 : m2);
        v.x = fminf(fmaxf((v.x - m) * f + m, 0.f), 255.f); c = (c == 2) ? 0 : c + 1;
        m = (c == 0) ? m0 : ((c == 1) ? m1 : m2);
        v.y = fminf(fmaxf((v.y - m) * f + m, 0.f), 255.f); c = (c == 2) ? 0 : c + 1;
        m = (c == 0) ? m0 : ((c == 1) ? m1 : m2);
        v.z = fminf(fmaxf((v.z - m) * f + m, 0.f), 255.f); c = (c == 2) ? 0 : c + 1;
        m = (c == 0) ? m0 : ((c == 1) ? m1 : m2);
        v.w = fminf(fmaxf((v.w - m) * f + m, 0.f), 255.f);
        base[i4] = v;
    }
}

extern "C" void kernel_launch(void* const* d_in, const int* in_sizes, int n_in,
                              void* d_out, int out_size, void* d_ws, size_t ws_size,
                              hipStream_t stream) {
    const float* in       = (const float*)d_in[0];
    const int*   fh       = (const int*)d_in[1];
    const int*   fv       = (const int*)d_in[2];
    const float* angle    = (const float*)d_in[3];
    const float* zoom     = (const float*)d_in[4];
    const float* delta    = (const float*)d_in[5];
    const float* contrast = (const float*)d_in[6];
    float*  out  = (float*)d_out;
    double* sums = (double*)d_ws;

    // ws re-poisoned to 0xAA each call — zero the sum accumulators.
    hipMemsetAsync(d_ws, 0, BATCH * 3 * sizeof(double), stream);

    dim3 blk(256);
    dim3 g1(Ww / TW, Hh / TH, BATCH);        // 8 x 32 x 32 = 8192 blocks
    warp_fused<<<g1, blk, 0, stream>>>(in, fh, fv, angle, zoom, delta, out, sums);

    dim3 g2(96, BATCH);                      // 8 float4/thread over 96MB
    contrast_pass<<<g2, blk, 0, stream>>>(out, sums, contrast);
}